// Round 1
// 443.078 us; speedup vs baseline: 1.0358x; 1.0358x over previous
//
#include <hip/hip_runtime.h>
#include <math.h>

// Problem constants
#define BB   32
#define SS   512
#define EE   256
#define HH   8
#define LL   4
#define FFD  1024
#define DHD  32

constexpr float LN_EPS = 1e-5f;
constexpr int   NBSE   = BB * SS * EE;   // 4,194,304

typedef float  f32x4  __attribute__((ext_vector_type(4)));
typedef __bf16 bf16;
typedef __bf16 bf16x4 __attribute__((ext_vector_type(4)));
typedef __bf16 bf16x8 __attribute__((ext_vector_type(8)));

// async global->LDS, 16B per lane; LDS dest is wave-uniform base + lane*16B
__device__ __forceinline__ void glds16(const bf16* g, bf16* l) {
    __builtin_amdgcn_global_load_lds(
        (const __attribute__((address_space(1))) void*)g,
        (__attribute__((address_space(3))) void*)l,
        16, 0, 0);
}

// tanh-form GELU (|err| vs exact erf-GELU ~1e-3, safe within bf16 tolerance)
__device__ __forceinline__ float gelu_f(float x) {
    float u = x * x;
    float t = 1.5957691216057308f * x * (1.0f + 0.044715f * u);
    return x / (1.0f + __expf(-t));
}

// ---------------------------------------------------------------- weight prep
// weight transpose+convert: in [K][N] f32 -> out [N][K] bf16, layer = blockIdx.z
__global__ __launch_bounds__(256) void k_cvt_t(const float* __restrict__ in,
                                               bf16* __restrict__ out,
                                               int K, int N) {
    __shared__ float tile[32][33];
    in  += (size_t)blockIdx.z * K * N;
    out += (size_t)blockIdx.z * K * N;
    int n0 = blockIdx.x * 32, k0 = blockIdx.y * 32;
    int tx = threadIdx.x & 31, ty = threadIdx.x >> 5;   // 32 x 8
    #pragma unroll
    for (int i = 0; i < 32; i += 8)
        tile[ty + i][tx] = in[(size_t)(k0 + ty + i) * N + n0 + tx];
    __syncthreads();
    #pragma unroll
    for (int i = 0; i < 32; i += 8)
        out[(size_t)(n0 + ty + i) * K + k0 + tx] = (bf16)tile[tx][ty + i];
}

// QKV weight transpose: W[l][h][d][e] f32 -> Wt[l][h][e][d] bf16 (q scaled by 1/sqrt(DH))
__global__ __launch_bounds__(256) void k_cvt_qkv(const float* __restrict__ Wq,
                                                 const float* __restrict__ Wk,
                                                 const float* __restrict__ Wv,
                                                 bf16* __restrict__ Wqt,
                                                 bf16* __restrict__ Wkt,
                                                 bf16* __restrict__ Wvt) {
    __shared__ float tile[32][33];
    int lh = blockIdx.x;            // l*H + h
    int z  = blockIdx.y;            // 0=q,1=k,2=v
    const float* in = (z == 0 ? Wq : z == 1 ? Wk : Wv) + (size_t)lh * 1024;
    bf16* out       = (z == 0 ? Wqt : z == 1 ? Wkt : Wvt) + (size_t)lh * 1024;
    float scale = (z == 0) ? 0.17677669529663687f : 1.0f;
    int tx = threadIdx.x & 31, ty = threadIdx.x >> 5;
    #pragma unroll
    for (int i = 0; i < 32; i += 8)
        tile[ty + i][tx] = in[(ty + i) * 32 + tx];
    __syncthreads();
    #pragma unroll
    for (int i = 0; i < 32; i += 8)
        out[(ty + i) * 32 + tx] = (bf16)(tile[tx][ty + i] * scale);
}

// ---------------------------------------------------------------- fused (addpos+)LN+QKV (MFMA)
// grid (B, S/64); 4 waves, wave w owns 16 s-rows. Outputs q,k [bh][s][d], v [bh][d][s].
// ADDPOS: xin = x, computes h = x+pos, writes hout; else xin = h (hout unused).
template <bool ADDPOS>
__global__ __launch_bounds__(256) void k_lnqkv(const float* __restrict__ xin,
                                               const float* __restrict__ pos,
                                               float* __restrict__ hout,
                                               const bf16* __restrict__ Wqt,
                                               const bf16* __restrict__ Wkt,
                                               const bf16* __restrict__ Wvt,
                                               bf16* __restrict__ qb,
                                               bf16* __restrict__ kb,
                                               bf16* __restrict__ vb) {
    __shared__ __attribute__((aligned(16))) bf16 Xs[64 * 264];
    int b = blockIdx.x, s0 = blockIdx.y * 64;
    int tid = threadIdx.x, w = tid >> 6, lane = tid & 63;
    size_t rowoff = ((size_t)(b * SS + s0 + w * 16)) * EE + lane * 4;
    const float* hb = xin + rowoff;
    float4 pv;
    if (ADDPOS) pv = *(const float4*)(pos + lane * 4);
    float4 xr[16];
    #pragma unroll
    for (int i = 0; i < 16; i++)
        xr[i] = *(const float4*)(hb + (size_t)i * EE);
    if (ADDPOS) {
        #pragma unroll
        for (int i = 0; i < 16; i++) {
            xr[i].x += pv.x; xr[i].y += pv.y; xr[i].z += pv.z; xr[i].w += pv.w;
            *(float4*)(hout + rowoff + (size_t)i * EE) = xr[i];
        }
    }
    #pragma unroll
    for (int i = 0; i < 16; i++) {
        float4 v4 = xr[i];
        float sum = v4.x + v4.y + v4.z + v4.w;
        #pragma unroll
        for (int m = 1; m <= 32; m <<= 1) sum += __shfl_xor(sum, m, 64);
        float mean = sum * (1.0f / EE);
        float dx = v4.x - mean, dy = v4.y - mean, dz = v4.z - mean, dw = v4.w - mean;
        float ss = dx * dx + dy * dy + dz * dz + dw * dw;
        #pragma unroll
        for (int m = 1; m <= 32; m <<= 1) ss += __shfl_xor(ss, m, 64);
        float rstd = rsqrtf(ss * (1.0f / EE) + LN_EPS);
        bf16x4 o4 = { (bf16)(dx * rstd), (bf16)(dy * rstd), (bf16)(dz * rstd), (bf16)(dw * rstd) };
        *(bf16x4*)&Xs[(w * 16 + i) * 264 + lane * 4] = o4;
    }
    __syncthreads();
    int col = lane & 15, quad = lane >> 4;
    #pragma unroll
    for (int h = 0; h < HH; h++) {
        bf16x8 a = *(const bf16x8*)&Xs[(w * 16 + col) * 264 + h * 32 + quad * 8];
        size_t base = ((size_t)((b * HH + h) * SS) + s0 + w * 16) * DHD;
        #pragma unroll
        for (int nt = 0; nt < 2; nt++) {
            int e = nt * 16 + col;
            bf16x8 bq  = *(const bf16x8*)(Wqt + (h * 32 + e) * 32 + quad * 8);
            bf16x8 bk2 = *(const bf16x8*)(Wkt + (h * 32 + e) * 32 + quad * 8);
            bf16x8 bv2 = *(const bf16x8*)(Wvt + (h * 32 + e) * 32 + quad * 8);
            f32x4 z = {0.f, 0.f, 0.f, 0.f};
            f32x4 cq = __builtin_amdgcn_mfma_f32_16x16x32_bf16(a, bq, z, 0, 0, 0);
            f32x4 ck = __builtin_amdgcn_mfma_f32_16x16x32_bf16(a, bk2, z, 0, 0, 0);
            f32x4 cv = __builtin_amdgcn_mfma_f32_16x16x32_bf16(a, bv2, z, 0, 0, 0);
            #pragma unroll
            for (int r = 0; r < 4; r++) {
                qb[base + (quad * 4 + r) * DHD + e] = (bf16)cq[r];
                kb[base + (quad * 4 + r) * DHD + e] = (bf16)ck[r];
            }
            bf16x4 vv = { (bf16)cv[0], (bf16)cv[1], (bf16)cv[2], (bf16)cv[3] };
            *(bf16x4*)&vb[(((size_t)(b * HH + h)) * DHD + e) * SS + s0 + w * 16 + quad * 4] = vv;
        }
    }
}

// ---------------------------------------------------------------- MFMA flash attention v3
// S^T formulation: mfma(K-frag, Q-frag) -> C holds 4 consecutive KEYS per lane ->
// packed b64 P-write (stride 36 u16: conflict-free, 8B-aligned) -> 2x b64 ap read.
// Fixed-max softmax; 128-q tile (2 sub-tiles/wave); O bf16 concat layout [b][s][E].
// T5: s_setprio(1) around the per-tile MFMA/softmax cluster (attn-proven +4-7%).
#define ATT_LDK 40
#define ATT_LDV 264
#define ATT_LDP 36
__global__ __launch_bounds__(256) void k_attn(const bf16* __restrict__ Q,
                                              const bf16* __restrict__ K,
                                              const bf16* __restrict__ VT,
                                              bf16* __restrict__ O) {
    __shared__ __attribute__((aligned(16))) bf16 Ks[256 * ATT_LDK];
    __shared__ __attribute__((aligned(16))) bf16 Vs[32 * ATT_LDV];
    __shared__ __attribute__((aligned(16))) bf16 Ps[4][16 * ATT_LDP];
    int bh = blockIdx.x;
    int q0 = blockIdx.y * 128;
    int tid = threadIdx.x;
    int w = tid >> 6, lane = tid & 63;
    int col = lane & 15, quad = lane >> 4;
    bf16x8 aq[2];
    #pragma unroll
    for (int sub = 0; sub < 2; sub++)
        aq[sub] = *(const bf16x8*)(Q + ((size_t)(bh * SS + q0 + sub * 64 + w * 16 + col)) * DHD + quad * 8);
    float lr[2] = {0.f, 0.f};
    f32x4 oacc[2][2] = {};
    int ksr = tid >> 2, ksc = (tid & 3) * 8;   // K staging: 64 rows/iter x 32 d
    int vd  = tid >> 5, vso = (tid & 31) * 8;  // VT staging: 8 d-rows/pass x 256 s
    for (int ph = 0; ph < 2; ph++) {
        int t00 = ph * 256;
        __syncthreads();
        #pragma unroll
        for (int it = 0; it < 4; it++) {
            int rl = it * 64 + ksr;
            *(bf16x8*)&Ks[rl * ATT_LDK + ksc] =
                *(const bf16x8*)(K + ((size_t)(bh * SS + t00 + rl)) * DHD + ksc);
        }
        #pragma unroll
        for (int it = 0; it < 4; it++) {
            int d = it * 8 + vd;
            *(bf16x8*)&Vs[d * ATT_LDV + vso] =
                *(const bf16x8*)(VT + (((size_t)bh * DHD + d) * SS) + t00 + vso);
        }
        __syncthreads();
        #pragma unroll
        for (int i = 0; i < 8; i++) {
            bf16x8 bk[2], bv[2];
            #pragma unroll
            for (int nt = 0; nt < 2; nt++) {
                bk[nt] = *(const bf16x8*)&Ks[(i * 32 + nt * 16 + col) * ATT_LDK + quad * 8];
                bv[nt] = *(const bf16x8*)&Vs[(nt * 16 + col) * ATT_LDV + i * 32 + quad * 8];
            }
            __builtin_amdgcn_s_setprio(1);
            #pragma unroll
            for (int sub = 0; sub < 2; sub++) {
                // S^T tiles: C row = key (quad*4+r within nt tile), col = q-row
                #pragma unroll
                for (int nt = 0; nt < 2; nt++) {
                    f32x4 z = {0.f, 0.f, 0.f, 0.f};
                    f32x4 st = __builtin_amdgcn_mfma_f32_16x16x32_bf16(bk[nt], aq[sub], z, 0, 0, 0);
                    bf16x4 p4;
                    #pragma unroll
                    for (int r = 0; r < 4; r++) {
                        float p = __expf(st[r]);
                        lr[sub] += p;
                        p4[r] = (bf16)p;
                    }
                    // row = q-row (col), cols = keys nt*16+quad*4 .. +3 (contiguous)
                    *(bf16x4*)&Ps[w][col * ATT_LDP + nt * 16 + quad * 4] = p4;
                }
                // P A-frag: keys quad*8..+7 for q-row col (two 8B reads, 72B stride)
                bf16x4 apl = *(const bf16x4*)&Ps[w][col * ATT_LDP + quad * 8];
                bf16x4 aph = *(const bf16x4*)&Ps[w][col * ATT_LDP + quad * 8 + 4];
                bf16x8 ap;
                ap[0] = apl[0]; ap[1] = apl[1]; ap[2] = apl[2]; ap[3] = apl[3];
                ap[4] = aph[0]; ap[5] = aph[1]; ap[6] = aph[2]; ap[7] = aph[3];
                #pragma unroll
                for (int nt = 0; nt < 2; nt++)
                    oacc[sub][nt] = __builtin_amdgcn_mfma_f32_16x16x32_bf16(ap, bv[nt], oacc[sub][nt], 0, 0, 0);
            }
            __builtin_amdgcn_s_setprio(0);
        }
    }
    int b = bh >> 3, hh = bh & 7;
    #pragma unroll
    for (int sub = 0; sub < 2; sub++) {
        float ls = lr[sub];
        ls += __shfl_xor(ls, 16, 64);
        ls += __shfl_xor(ls, 32, 64);   // full row-sum for q-row 'col', replicated
        #pragma unroll
        for (int r = 0; r < 4; r++) {
            float lrow = __shfl(ls, quad * 4 + r, 64);   // l for q-row quad*4+r
            float inv = 1.0f / lrow;
            int row = q0 + sub * 64 + w * 16 + quad * 4 + r;
            size_t ob = ((size_t)(b * SS + row)) * EE + hh * 32;
            O[ob + col]      = (bf16)(oacc[sub][0][r] * inv);
            O[ob + 16 + col] = (bf16)(oacc[sub][1][r] * inv);
        }
    }
}

// ---------------------------------------------------------------- FFN1 fused: res+LN prologue + GEMM
// tile 64x256, 4 waves (wave = 64-col strip). A-panel (LN(h+ob)) computed in prologue,
// resident in LDS for all 8 K-steps (XOR-swizzled: elem ^= (row&7)<<3 -> 2-way/free reads).
// B staged per K-step via glds16 with pre-swizzled SOURCE (linear LDS dest, rule #21),
// read with matching XOR ((c&3)<<3): 8-way -> ~2-way conflicts.
__global__ __launch_bounds__(256, 3) void k_gemm1f(const bf16* __restrict__ ob,
                                                   const float* __restrict__ hb,
                                                   const bf16* __restrict__ Bt,
                                                   const float* __restrict__ bias,
                                                   bf16* __restrict__ C) {
    __shared__ __attribute__((aligned(16))) bf16 As[64 * 256];   // 32 KB, resident
    __shared__ __attribute__((aligned(16))) bf16 Bs[256 * 32];   // 16 KB, per-step
    int tid = threadIdx.x, w = tid >> 6, lane = tid & 63;
    int col = lane & 15, quad = lane >> 4;
    int row0 = blockIdx.x * 64, col0 = blockIdx.y * 256;

    // ---- fused residual + LN prologue: wave w computes rows w*16 .. w*16+15
    #pragma unroll 4
    for (int rr = 0; rr < 16; rr++) {
        int r = w * 16 + rr;
        size_t g = (size_t)(row0 + r) * EE + lane * 4;
        float4 h4 = *(const float4*)(hb + g);
        bf16x4 o4 = *(const bf16x4*)(ob + g);
        float v0 = h4.x + (float)o4[0], v1 = h4.y + (float)o4[1];
        float v2 = h4.z + (float)o4[2], v3 = h4.w + (float)o4[3];
        float s1 = v0 + v1 + v2 + v3;
        float s2 = v0 * v0 + v1 * v1 + v2 * v2 + v3 * v3;
        #pragma unroll
        for (int m = 1; m <= 32; m <<= 1) {
            s1 += __shfl_xor(s1, m, 64);
            s2 += __shfl_xor(s2, m, 64);
        }
        float mean = s1 * (1.0f / EE);
        float rstd = rsqrtf(s2 * (1.0f / EE) - mean * mean + LN_EPS);
        bf16x4 a4 = { (bf16)((v0 - mean) * rstd), (bf16)((v1 - mean) * rstd),
                      (bf16)((v2 - mean) * rstd), (bf16)((v3 - mean) * rstd) };
        *(bf16x4*)&As[r * 256 + ((lane * 4) ^ ((r & 7) << 3))] = a4;
    }

    int bc = lane >> 2;      // col within a 16-col staging chunk
    int bp = lane & 3;       // 16B k-slot within a 64B col-row
    f32x4 acc[4][4] = {};
    for (int k0 = 0; k0 < EE; k0 += 32) {
        __syncthreads();     // Bs free to overwrite (1st iter: As prologue visible)
        #pragma unroll
        for (int i = 0; i < 4; i++) {
            int c = (w * 4 + i) * 16 + bc;
            glds16(Bt + (size_t)(col0 + c) * EE + k0 + ((bp ^ (c & 3)) * 8),
                   &Bs[(w * 4 + i) * 16 * 32]);
        }
        __syncthreads();
        bf16x8 af[4], bf_[4];
        #pragma unroll
        for (int mt = 0; mt < 4; mt++) {
            int r = mt * 16 + col;
            af[mt] = *(const bf16x8*)&As[r * 256 + ((k0 + quad * 8) ^ ((r & 7) << 3))];
        }
        #pragma unroll
        for (int nt = 0; nt < 4; nt++) {
            int c = w * 64 + nt * 16 + col;
            bf_[nt] = *(const bf16x8*)&Bs[c * 32 + ((quad * 8) ^ ((c & 3) << 3))];
        }
        #pragma unroll
        for (int mt = 0; mt < 4; mt++)
            #pragma unroll
            for (int nt = 0; nt < 4; nt++)
                acc[mt][nt] = __builtin_amdgcn_mfma_f32_16x16x32_bf16(bf_[nt], af[mt], acc[mt][nt], 0, 0, 0);
    }
    #pragma unroll
    for (int mt = 0; mt < 4; mt++) {
        int row = row0 + mt * 16 + col;
        #pragma unroll
        for (int nt = 0; nt < 4; nt++) {
            int cc = col0 + w * 64 + nt * 16 + quad * 4;
            float4 b4 = *(const float4*)&bias[cc];
            bf16x4 ov;
            ov[0] = (bf16)gelu_f(acc[mt][nt][0] + b4.x);
            ov[1] = (bf16)gelu_f(acc[mt][nt][1] + b4.y);
            ov[2] = (bf16)gelu_f(acc[mt][nt][2] + b4.z);
            ov[3] = (bf16)gelu_f(acc[mt][nt][3] + b4.w);
            *(bf16x4*)&C[(size_t)row * FFD + cc] = ov;
        }
    }
}

// ---------------------------------------------------------------- FFN2: BK=64 GEMM (half the barriers)
// Same tile/output mapping as before; A/B staged with pre-swizzled source
// (elem ^= (row&7)<<3 within the 128B row) -> conflict-free fragment reads.
__global__ __launch_bounds__(256) void k_gemm2(const bf16* __restrict__ A,
                                               const bf16* __restrict__ Bt,
                                               const float* __restrict__ bias,
                                               const bf16* __restrict__ ob,
                                               const float* __restrict__ hb,
                                               float* __restrict__ Cf) {
    __shared__ __attribute__((aligned(16))) bf16 As[128 * 64];   // 16 KB
    __shared__ __attribute__((aligned(16))) bf16 Bs[64 * 64];    // 8 KB
    int tid = threadIdx.x, w = tid >> 6, lane = tid & 63;
    int col = lane & 15, quad = lane >> 4;
    int row0 = blockIdx.x * 128, col0 = blockIdx.y * 64;
    int srow = lane >> 3;    // row within 8-row staging chunk
    int spos = lane & 7;     // 16B k-slot within 128B row
    f32x4 acc[2][4] = {};
    for (int k0 = 0; k0 < FFD; k0 += 64) {
        __syncthreads();
        #pragma unroll
        for (int i = 0; i < 4; i++) {
            int r = (w * 4 + i) * 8 + srow;
            glds16(A + (size_t)(row0 + r) * FFD + k0 + ((spos ^ (r & 7)) * 8),
                   &As[(w * 4 + i) * 8 * 64]);
        }
        #pragma unroll
        for (int i = 0; i < 2; i++) {
            int r = (w * 2 + i) * 8 + srow;
            glds16(Bt + (size_t)(col0 + r) * FFD + k0 + ((spos ^ (r & 7)) * 8),
                   &Bs[(w * 2 + i) * 8 * 64]);
        }
        __syncthreads();
        bf16x8 af[2][2], bf_[4][2];
        #pragma unroll
        for (int mt = 0; mt < 2; mt++) {
            int r = w * 32 + mt * 16 + col;
            #pragma unroll
            for (int kk = 0; kk < 2; kk++)
                af[mt][kk] = *(const bf16x8*)&As[r * 64 + ((kk * 32 + quad * 8) ^ ((r & 7) << 3))];
        }
        #pragma unroll
        for (int nt = 0; nt < 4; nt++) {
            int r = nt * 16 + col;
            #pragma unroll
            for (int kk = 0; kk < 2; kk++)
                bf_[nt][kk] = *(const bf16x8*)&Bs[r * 64 + ((kk * 32 + quad * 8) ^ ((r & 7) << 3))];
        }
        #pragma unroll
        for (int kk = 0; kk < 2; kk++)
            #pragma unroll
            for (int mt = 0; mt < 2; mt++)
                #pragma unroll
                for (int nt = 0; nt < 4; nt++)
                    acc[mt][nt] = __builtin_amdgcn_mfma_f32_16x16x32_bf16(bf_[nt][kk], af[mt][kk], acc[mt][nt], 0, 0, 0);
    }
    #pragma unroll
    for (int mt = 0; mt < 2; mt++) {
        int row = row0 + w * 32 + mt * 16 + col;
        #pragma unroll
        for (int nt = 0; nt < 4; nt++) {
            int cc = col0 + nt * 16 + quad * 4;
            float4 b4 = *(const float4*)&bias[cc];
            float4 h4 = *(const float4*)&hb[(size_t)row * EE + cc];
            bf16x4 o4 = *(const bf16x4*)&ob[(size_t)row * EE + cc];
            float4 out;
            out.x = acc[mt][nt][0] + b4.x + h4.x + (float)o4[0];
            out.y = acc[mt][nt][1] + b4.y + h4.y + (float)o4[1];
            out.z = acc[mt][nt][2] + b4.z + h4.z + (float)o4[2];
            out.w = acc[mt][nt][3] + b4.w + h4.w + (float)o4[3];
            *(float4*)&Cf[(size_t)row * EE + cc] = out;
        }
    }
}

// ---------------------------------------------------------------- launch
extern "C" void kernel_launch(void* const* d_in, const int* in_sizes, int n_in,
                              void* d_out, int out_size, void* d_ws, size_t ws_size,
                              hipStream_t stream) {
    (void)in_sizes; (void)n_in; (void)out_size; (void)ws_size;
    const float* x   = (const float*)d_in[0];
    const float* pos = (const float*)d_in[1];
    const float* Wq  = (const float*)d_in[2];
    const float* Wk  = (const float*)d_in[3];
    const float* Wv  = (const float*)d_in[4];
    const float* W1  = (const float*)d_in[5];
    const float* b1  = (const float*)d_in[6];
    const float* W2  = (const float*)d_in[7];
    const float* b2  = (const float*)d_in[8];

    float* ws = (float*)d_ws;
    size_t N = (size_t)NBSE;
    float* h  = ws;                          // [0 .. 16MB) f32 residual stream
    bf16* ob  = (bf16*)(ws + N);             // [16 .. 24MB) attention out, concat layout
    bf16* qb  = (bf16*)(ws + 2 * N);         // [32 .. 40MB)
    bf16* kb  = qb + N;                      // [40 .. 48MB)
    bf16* vb  = kb + N;                      // [48 .. 56MB) (VT layout [bh][d][s])
    bf16* ffb = (bf16*)(ws + 2 * N);         // [32 .. 64MB) overlays qb,kb,vb (dead by FFN1)
    bf16* W1t = (bf16*)(ws + 4 * N);         // [64MB ..)
    bf16* W2t = W1t + (size_t)LL * EE * FFD;
    bf16* Wqt = W2t + (size_t)LL * EE * FFD;
    bf16* Wkt = Wqt + (size_t)LL * HH * DHD * DHD;
    bf16* Wvt = Wkt + (size_t)LL * HH * DHD * DHD;

    k_cvt_t<<<dim3(FFD / 32, EE / 32, LL), 256, 0, stream>>>(W1, W1t, EE, FFD);
    k_cvt_t<<<dim3(EE / 32, FFD / 32, LL), 256, 0, stream>>>(W2, W2t, FFD, EE);
    k_cvt_qkv<<<dim3(LL * HH, 3), 256, 0, stream>>>(Wq, Wk, Wv, Wqt, Wkt, Wvt);
    for (int l = 0; l < LL; l++) {
        if (l == 0)
            k_lnqkv<true><<<dim3(BB, SS / 64), 256, 0, stream>>>(
                x, pos, h, Wqt, Wkt, Wvt, qb, kb, vb);
        else
            k_lnqkv<false><<<dim3(BB, SS / 64), 256, 0, stream>>>(
                h, nullptr, nullptr,
                Wqt + (size_t)l * HH * DHD * DHD, Wkt + (size_t)l * HH * DHD * DHD,
                Wvt + (size_t)l * HH * DHD * DHD, qb, kb, vb);
        k_attn<<<dim3(BB * HH, SS / 128), 256, 0, stream>>>(qb, kb, vb, ob);
        k_gemm1f<<<dim3(BB * SS / 64, FFD / 256), 256, 0, stream>>>(
            ob, h, W1t + (size_t)l * FFD * EE, b1 + (size_t)l * FFD, ffb);
        float* outp = (l == LL - 1) ? (float*)d_out : h;
        k_gemm2<<<dim3(BB * SS / 128, EE / 64), 256, 0, stream>>>(
            ffb, W2t + (size_t)l * EE * FFD, b2 + (size_t)l * EE, ob, h, outp);
    }
}

// Round 2
// 441.034 us; speedup vs baseline: 1.0406x; 1.0046x over previous
//
#include <hip/hip_runtime.h>
#include <math.h>

// Problem constants
#define BB   32
#define SS   512
#define EE   256
#define HH   8
#define LL   4
#define FFD  1024
#define DHD  32

constexpr float LN_EPS = 1e-5f;
constexpr int   NBSE   = BB * SS * EE;   // 4,194,304

typedef float  f32x4  __attribute__((ext_vector_type(4)));
typedef __bf16 bf16;
typedef __bf16 bf16x4 __attribute__((ext_vector_type(4)));
typedef __bf16 bf16x8 __attribute__((ext_vector_type(8)));

// async global->LDS, 16B per lane; LDS dest is wave-uniform base + lane*16B
__device__ __forceinline__ void glds16(const bf16* g, bf16* l) {
    __builtin_amdgcn_global_load_lds(
        (const __attribute__((address_space(1))) void*)g,
        (__attribute__((address_space(3))) void*)l,
        16, 0, 0);
}

// tanh-form GELU (|err| vs exact erf-GELU ~1e-3, safe within bf16 tolerance)
__device__ __forceinline__ float gelu_f(float x) {
    float u = x * x;
    float t = 1.5957691216057308f * x * (1.0f + 0.044715f * u);
    return x / (1.0f + __expf(-t));
}

// ---------------------------------------------------------------- merged weight prep
// blocks [0,1024): W1 [256][1024] -> W1t [1024][256]
// blocks [1024,2048): W2 [1024][256] -> W2t [256][1024]
// blocks [2048,2144): QKV per-head 32x32 transpose (+1/sqrt(DH) on Q)
__global__ __launch_bounds__(256) void k_prep(const float* __restrict__ W1,
                                              const float* __restrict__ W2,
                                              const float* __restrict__ Wq,
                                              const float* __restrict__ Wk,
                                              const float* __restrict__ Wv,
                                              bf16* __restrict__ W1t,
                                              bf16* __restrict__ W2t,
                                              bf16* __restrict__ Wqt,
                                              bf16* __restrict__ Wkt,
                                              bf16* __restrict__ Wvt) {
    __shared__ float tile[32][33];
    int bid = blockIdx.x;
    int tx = threadIdx.x & 31, ty = threadIdx.x >> 5;   // 32 x 8
    if (bid < 2048) {
        bool isw2 = bid >= 1024;
        int id = isw2 ? bid - 1024 : bid;
        int K = isw2 ? FFD : EE, N = isw2 ? EE : FFD;
        int l = id >> 8, rem = id & 255;
        int n0, k0;
        if (isw2) { n0 = (rem & 7) * 32;  k0 = (rem >> 3) * 32; }
        else      { n0 = (rem & 31) * 32; k0 = (rem >> 5) * 32; }
        const float* in = (isw2 ? W2 : W1) + (size_t)l * K * N;
        bf16* out       = (isw2 ? W2t : W1t) + (size_t)l * K * N;
        #pragma unroll
        for (int i = 0; i < 32; i += 8)
            tile[ty + i][tx] = in[(size_t)(k0 + ty + i) * N + n0 + tx];
        __syncthreads();
        #pragma unroll
        for (int i = 0; i < 32; i += 8)
            out[(size_t)(n0 + ty + i) * K + k0 + tx] = (bf16)tile[tx][ty + i];
    } else {
        int id = bid - 2048;
        int lh = id & 31, z = id >> 5;
        const float* in = (z == 0 ? Wq : z == 1 ? Wk : Wv) + (size_t)lh * 1024;
        bf16* out       = (z == 0 ? Wqt : z == 1 ? Wkt : Wvt) + (size_t)lh * 1024;
        float scale = (z == 0) ? 0.17677669529663687f : 1.0f;
        #pragma unroll
        for (int i = 0; i < 32; i += 8)
            tile[ty + i][tx] = in[(ty + i) * 32 + tx];
        __syncthreads();
        #pragma unroll
        for (int i = 0; i < 32; i += 8)
            out[(ty + i) * 32 + tx] = (bf16)(tile[tx][ty + i] * scale);
    }
}

// ---------------------------------------------------------------- fused (addpos+)LN+QKV (MFMA)
// grid (B, S/64); 4 waves, wave w owns 16 s-rows. Outputs q,k [bh][s][d], v [bh][d][s].
// Q/K use SWAPPED mfma operands (W-frag as A) -> C has token=lane&15, e=quad*4+r ->
// one bf16x4 vector store per tile (was 8 scalar stores). V keeps original order.
template <bool ADDPOS>
__global__ __launch_bounds__(256) void k_lnqkv(const float* __restrict__ xin,
                                               const float* __restrict__ pos,
                                               float* __restrict__ hout,
                                               const bf16* __restrict__ Wqt,
                                               const bf16* __restrict__ Wkt,
                                               const bf16* __restrict__ Wvt,
                                               bf16* __restrict__ qb,
                                               bf16* __restrict__ kb,
                                               bf16* __restrict__ vb) {
    __shared__ __attribute__((aligned(16))) bf16 Xs[64 * 264];
    int b = blockIdx.x, s0 = blockIdx.y * 64;
    int tid = threadIdx.x, w = tid >> 6, lane = tid & 63;
    size_t rowoff = ((size_t)(b * SS + s0 + w * 16)) * EE + lane * 4;
    const float* hb = xin + rowoff;
    float4 pv;
    if (ADDPOS) pv = *(const float4*)(pos + lane * 4);
    float4 xr[16];
    #pragma unroll
    for (int i = 0; i < 16; i++)
        xr[i] = *(const float4*)(hb + (size_t)i * EE);
    if (ADDPOS) {
        #pragma unroll
        for (int i = 0; i < 16; i++) {
            xr[i].x += pv.x; xr[i].y += pv.y; xr[i].z += pv.z; xr[i].w += pv.w;
            *(float4*)(hout + rowoff + (size_t)i * EE) = xr[i];
        }
    }
    #pragma unroll
    for (int i = 0; i < 16; i++) {
        float4 v4 = xr[i];
        float sum = v4.x + v4.y + v4.z + v4.w;
        #pragma unroll
        for (int m = 1; m <= 32; m <<= 1) sum += __shfl_xor(sum, m, 64);
        float mean = sum * (1.0f / EE);
        float dx = v4.x - mean, dy = v4.y - mean, dz = v4.z - mean, dw = v4.w - mean;
        float ss = dx * dx + dy * dy + dz * dz + dw * dw;
        #pragma unroll
        for (int m = 1; m <= 32; m <<= 1) ss += __shfl_xor(ss, m, 64);
        float rstd = rsqrtf(ss * (1.0f / EE) + LN_EPS);
        bf16x4 o4 = { (bf16)(dx * rstd), (bf16)(dy * rstd), (bf16)(dz * rstd), (bf16)(dw * rstd) };
        *(bf16x4*)&Xs[(w * 16 + i) * 264 + lane * 4] = o4;
    }
    __syncthreads();
    int col = lane & 15, quad = lane >> 4;
    #pragma unroll
    for (int h = 0; h < HH; h++) {
        bf16x8 a = *(const bf16x8*)&Xs[(w * 16 + col) * 264 + h * 32 + quad * 8];
        size_t base = ((size_t)((b * HH + h) * SS) + s0 + w * 16) * DHD;
        #pragma unroll
        for (int nt = 0; nt < 2; nt++) {
            int e = nt * 16 + col;
            bf16x8 bq  = *(const bf16x8*)(Wqt + (h * 32 + e) * 32 + quad * 8);
            bf16x8 bk2 = *(const bf16x8*)(Wkt + (h * 32 + e) * 32 + quad * 8);
            bf16x8 bv2 = *(const bf16x8*)(Wvt + (h * 32 + e) * 32 + quad * 8);
            f32x4 z = {0.f, 0.f, 0.f, 0.f};
            // swapped operands: C[m=e(within tile), n=token] -> lane holds 4 consecutive e
            f32x4 cq = __builtin_amdgcn_mfma_f32_16x16x32_bf16(bq, a, z, 0, 0, 0);
            f32x4 ck = __builtin_amdgcn_mfma_f32_16x16x32_bf16(bk2, a, z, 0, 0, 0);
            // original order for V: lane holds 4 consecutive tokens for e=col tile
            f32x4 cv = __builtin_amdgcn_mfma_f32_16x16x32_bf16(a, bv2, z, 0, 0, 0);
            bf16x4 q4 = { (bf16)cq[0], (bf16)cq[1], (bf16)cq[2], (bf16)cq[3] };
            bf16x4 k4 = { (bf16)ck[0], (bf16)ck[1], (bf16)ck[2], (bf16)ck[3] };
            size_t tb = base + (size_t)col * DHD + nt * 16 + quad * 4;
            *(bf16x4*)&qb[tb] = q4;
            *(bf16x4*)&kb[tb] = k4;
            bf16x4 vv = { (bf16)cv[0], (bf16)cv[1], (bf16)cv[2], (bf16)cv[3] };
            *(bf16x4*)&vb[(((size_t)(b * HH + h)) * DHD + e) * SS + s0 + w * 16 + quad * 4] = vv;
        }
    }
}

// ---------------------------------------------------------------- MFMA flash attention v3
// S^T formulation + T14 reg-prefetch: phase-1 K/V global loads issued right after
// phase-0 LDS writes, hidden under phase-0 compute (the __syncthreads vmcnt(0)
// at phase-1 top then waits ~0). T5 setprio around MFMA/softmax cluster.
#define ATT_LDK 40
#define ATT_LDV 264
#define ATT_LDP 36
__global__ __launch_bounds__(256) void k_attn(const bf16* __restrict__ Q,
                                              const bf16* __restrict__ K,
                                              const bf16* __restrict__ VT,
                                              bf16* __restrict__ O) {
    __shared__ __attribute__((aligned(16))) bf16 Ks[256 * ATT_LDK];
    __shared__ __attribute__((aligned(16))) bf16 Vs[32 * ATT_LDV];
    __shared__ __attribute__((aligned(16))) bf16 Ps[4][16 * ATT_LDP];
    int bh = blockIdx.x;
    int q0 = blockIdx.y * 128;
    int tid = threadIdx.x;
    int w = tid >> 6, lane = tid & 63;
    int col = lane & 15, quad = lane >> 4;
    bf16x8 aq[2];
    #pragma unroll
    for (int sub = 0; sub < 2; sub++)
        aq[sub] = *(const bf16x8*)(Q + ((size_t)(bh * SS + q0 + sub * 64 + w * 16 + col)) * DHD + quad * 8);
    float lr[2] = {0.f, 0.f};
    f32x4 oacc[2][2] = {};
    int ksr = tid >> 2, ksc = (tid & 3) * 8;   // K staging: 64 rows/iter x 32 d
    int vd  = tid >> 5, vso = (tid & 31) * 8;  // VT staging: 8 d-rows/pass x 256 s
    bf16x8 kr[4], vr[4];
    #pragma unroll
    for (int it = 0; it < 4; it++) {
        kr[it] = *(const bf16x8*)(K + ((size_t)(bh * SS + it * 64 + ksr)) * DHD + ksc);
        vr[it] = *(const bf16x8*)(VT + (((size_t)bh * DHD + it * 8 + vd) * SS) + vso);
    }
    for (int ph = 0; ph < 2; ph++) {
        __syncthreads();
        #pragma unroll
        for (int it = 0; it < 4; it++) {
            *(bf16x8*)&Ks[(it * 64 + ksr) * ATT_LDK + ksc] = kr[it];
            *(bf16x8*)&Vs[(it * 8 + vd) * ATT_LDV + vso] = vr[it];
        }
        if (ph == 0) {   // issue phase-1 loads; they fly under phase-0 compute
            #pragma unroll
            for (int it = 0; it < 4; it++) {
                kr[it] = *(const bf16x8*)(K + ((size_t)(bh * SS + 256 + it * 64 + ksr)) * DHD + ksc);
                vr[it] = *(const bf16x8*)(VT + (((size_t)bh * DHD + it * 8 + vd) * SS) + 256 + vso);
            }
        }
        __syncthreads();
        #pragma unroll
        for (int i = 0; i < 8; i++) {
            bf16x8 bk[2], bv[2];
            #pragma unroll
            for (int nt = 0; nt < 2; nt++) {
                bk[nt] = *(const bf16x8*)&Ks[(i * 32 + nt * 16 + col) * ATT_LDK + quad * 8];
                bv[nt] = *(const bf16x8*)&Vs[(nt * 16 + col) * ATT_LDV + i * 32 + quad * 8];
            }
            __builtin_amdgcn_s_setprio(1);
            #pragma unroll
            for (int sub = 0; sub < 2; sub++) {
                #pragma unroll
                for (int nt = 0; nt < 2; nt++) {
                    f32x4 z = {0.f, 0.f, 0.f, 0.f};
                    f32x4 st = __builtin_amdgcn_mfma_f32_16x16x32_bf16(bk[nt], aq[sub], z, 0, 0, 0);
                    bf16x4 p4;
                    #pragma unroll
                    for (int r = 0; r < 4; r++) {
                        float p = __expf(st[r]);
                        lr[sub] += p;
                        p4[r] = (bf16)p;
                    }
                    *(bf16x4*)&Ps[w][col * ATT_LDP + nt * 16 + quad * 4] = p4;
                }
                bf16x4 apl = *(const bf16x4*)&Ps[w][col * ATT_LDP + quad * 8];
                bf16x4 aph = *(const bf16x4*)&Ps[w][col * ATT_LDP + quad * 8 + 4];
                bf16x8 ap;
                ap[0] = apl[0]; ap[1] = apl[1]; ap[2] = apl[2]; ap[3] = apl[3];
                ap[4] = aph[0]; ap[5] = aph[1]; ap[6] = aph[2]; ap[7] = aph[3];
                #pragma unroll
                for (int nt = 0; nt < 2; nt++)
                    oacc[sub][nt] = __builtin_amdgcn_mfma_f32_16x16x32_bf16(ap, bv[nt], oacc[sub][nt], 0, 0, 0);
            }
            __builtin_amdgcn_s_setprio(0);
        }
    }
    int b = bh >> 3, hh = bh & 7;
    #pragma unroll
    for (int sub = 0; sub < 2; sub++) {
        float ls = lr[sub];
        ls += __shfl_xor(ls, 16, 64);
        ls += __shfl_xor(ls, 32, 64);
        #pragma unroll
        for (int r = 0; r < 4; r++) {
            float lrow = __shfl(ls, quad * 4 + r, 64);
            float inv = 1.0f / lrow;
            int row = q0 + sub * 64 + w * 16 + quad * 4 + r;
            size_t ob = ((size_t)(b * SS + row)) * EE + hh * 32;
            O[ob + col]      = (bf16)(oacc[sub][0][r] * inv);
            O[ob + 16 + col] = (bf16)(oacc[sub][1][r] * inv);
        }
    }
}

// ---------------------------------------------------------------- FFN1 fused: res+LN prologue + GEMM
// tile 64x256; A resident (XOR-swizzled). B double-buffered with counted-vmcnt
// prefetch: stage(next) issued before compute(cur); raw s_barrier (no vmcnt(0) drain).
__global__ __launch_bounds__(256, 2) void k_gemm1f(const bf16* __restrict__ ob,
                                                   const float* __restrict__ hb,
                                                   const bf16* __restrict__ Bt,
                                                   const float* __restrict__ bias,
                                                   bf16* __restrict__ C) {
    __shared__ __attribute__((aligned(16))) bf16 As[64 * 256];     // 32 KB, resident
    __shared__ __attribute__((aligned(16))) bf16 Bs[2][256 * 32];  // 2 x 16 KB
    int tid = threadIdx.x, w = tid >> 6, lane = tid & 63;
    int col = lane & 15, quad = lane >> 4;
    int row0 = blockIdx.x * 64, col0 = blockIdx.y * 256;

    // ---- fused residual + LN prologue: wave w computes rows w*16 .. w*16+15
    #pragma unroll 4
    for (int rr = 0; rr < 16; rr++) {
        int r = w * 16 + rr;
        size_t g = (size_t)(row0 + r) * EE + lane * 4;
        float4 h4 = *(const float4*)(hb + g);
        bf16x4 o4 = *(const bf16x4*)(ob + g);
        float v0 = h4.x + (float)o4[0], v1 = h4.y + (float)o4[1];
        float v2 = h4.z + (float)o4[2], v3 = h4.w + (float)o4[3];
        float s1 = v0 + v1 + v2 + v3;
        float s2 = v0 * v0 + v1 * v1 + v2 * v2 + v3 * v3;
        #pragma unroll
        for (int m = 1; m <= 32; m <<= 1) {
            s1 += __shfl_xor(s1, m, 64);
            s2 += __shfl_xor(s2, m, 64);
        }
        float mean = s1 * (1.0f / EE);
        float rstd = rsqrtf(s2 * (1.0f / EE) - mean * mean + LN_EPS);
        bf16x4 a4 = { (bf16)((v0 - mean) * rstd), (bf16)((v1 - mean) * rstd),
                      (bf16)((v2 - mean) * rstd), (bf16)((v3 - mean) * rstd) };
        *(bf16x4*)&As[r * 256 + ((lane * 4) ^ ((r & 7) << 3))] = a4;
    }

    int bc = lane >> 2;      // col within a 16-col staging chunk
    int bp = lane & 3;       // 16B k-slot within a 64B col-row
    auto stageB = [&](int buf, int k0) {
        #pragma unroll
        for (int i = 0; i < 4; i++) {
            int c = (w * 4 + i) * 16 + bc;
            glds16(Bt + (size_t)(col0 + c) * EE + k0 + ((bp ^ (c & 3)) * 8),
                   &Bs[buf][(w * 4 + i) * 16 * 32]);
        }
    };
    // publish As (ds_writes) before first raw barrier
    asm volatile("s_waitcnt lgkmcnt(0)" ::: "memory");
    stageB(0, 0);
    f32x4 acc[4][4] = {};
    for (int t = 0; t < 8; t++) {
        if (t < 7) {
            stageB((t + 1) & 1, (t + 1) * 32);
            asm volatile("s_waitcnt vmcnt(4)" ::: "memory");  // cur buf done, next in flight
        } else {
            asm volatile("s_waitcnt vmcnt(0)" ::: "memory");
        }
        __builtin_amdgcn_s_barrier();
        int k0 = t * 32, buf = t & 1;
        bf16x8 af[4], bf_[4];
        #pragma unroll
        for (int mt = 0; mt < 4; mt++) {
            int r = mt * 16 + col;
            af[mt] = *(const bf16x8*)&As[r * 256 + ((k0 + quad * 8) ^ ((r & 7) << 3))];
        }
        #pragma unroll
        for (int nt = 0; nt < 4; nt++) {
            int c = w * 64 + nt * 16 + col;
            bf_[nt] = *(const bf16x8*)&Bs[buf][c * 32 + ((quad * 8) ^ ((c & 3) << 3))];
        }
        #pragma unroll
        for (int mt = 0; mt < 4; mt++)
            #pragma unroll
            for (int nt = 0; nt < 4; nt++)
                acc[mt][nt] = __builtin_amdgcn_mfma_f32_16x16x32_bf16(bf_[nt], af[mt], acc[mt][nt], 0, 0, 0);
        __builtin_amdgcn_s_barrier();   // all reads of Bs[buf] done -> overwrite safe
    }
    #pragma unroll
    for (int mt = 0; mt < 4; mt++) {
        int row = row0 + mt * 16 + col;
        #pragma unroll
        for (int nt = 0; nt < 4; nt++) {
            int cc = col0 + w * 64 + nt * 16 + quad * 4;
            float4 b4 = *(const float4*)&bias[cc];
            bf16x4 ov;
            ov[0] = (bf16)gelu_f(acc[mt][nt][0] + b4.x);
            ov[1] = (bf16)gelu_f(acc[mt][nt][1] + b4.y);
            ov[2] = (bf16)gelu_f(acc[mt][nt][2] + b4.z);
            ov[3] = (bf16)gelu_f(acc[mt][nt][3] + b4.w);
            *(bf16x4*)&C[(size_t)row * FFD + cc] = ov;
        }
    }
}

// ---------------------------------------------------------------- FFN2: BK=64, double-buffered counted-vmcnt
__global__ __launch_bounds__(256, 3) void k_gemm2(const bf16* __restrict__ A,
                                                  const bf16* __restrict__ Bt,
                                                  const float* __restrict__ bias,
                                                  const bf16* __restrict__ ob,
                                                  const float* __restrict__ hb,
                                                  float* __restrict__ Cf) {
    __shared__ __attribute__((aligned(16))) bf16 As[2][128 * 64];  // 2 x 16 KB
    __shared__ __attribute__((aligned(16))) bf16 Bs[2][64 * 64];   // 2 x 8 KB
    int tid = threadIdx.x, w = tid >> 6, lane = tid & 63;
    int col = lane & 15, quad = lane >> 4;
    int row0 = blockIdx.x * 128, col0 = blockIdx.y * 64;
    int srow = lane >> 3;    // row within 8-row staging chunk
    int spos = lane & 7;     // 16B k-slot within 128B row
    auto stageAB = [&](int buf, int k0) {
        #pragma unroll
        for (int i = 0; i < 4; i++) {
            int r = (w * 4 + i) * 8 + srow;
            glds16(A + (size_t)(row0 + r) * FFD + k0 + ((spos ^ (r & 7)) * 8),
                   &As[buf][(w * 4 + i) * 8 * 64]);
        }
        #pragma unroll
        for (int i = 0; i < 2; i++) {
            int r = (w * 2 + i) * 8 + srow;
            glds16(Bt + (size_t)(col0 + r) * FFD + k0 + ((spos ^ (r & 7)) * 8),
                   &Bs[buf][(w * 2 + i) * 8 * 64]);
        }
    };
    stageAB(0, 0);
    f32x4 acc[2][4] = {};
    for (int t = 0; t < 16; t++) {
        if (t < 15) {
            stageAB((t + 1) & 1, (t + 1) * 64);
            asm volatile("s_waitcnt vmcnt(6)" ::: "memory");
        } else {
            asm volatile("s_waitcnt vmcnt(0)" ::: "memory");
        }
        __builtin_amdgcn_s_barrier();
        int buf = t & 1;
        bf16x8 af[2][2], bf_[4][2];
        #pragma unroll
        for (int mt = 0; mt < 2; mt++) {
            int r = w * 32 + mt * 16 + col;
            #pragma unroll
            for (int kk = 0; kk < 2; kk++)
                af[mt][kk] = *(const bf16x8*)&As[buf][r * 64 + ((kk * 32 + quad * 8) ^ ((r & 7) << 3))];
        }
        #pragma unroll
        for (int nt = 0; nt < 4; nt++) {
            int r = nt * 16 + col;
            #pragma unroll
            for (int kk = 0; kk < 2; kk++)
                bf_[nt][kk] = *(const bf16x8*)&Bs[buf][r * 64 + ((kk * 32 + quad * 8) ^ ((r & 7) << 3))];
        }
        #pragma unroll
        for (int kk = 0; kk < 2; kk++)
            #pragma unroll
            for (int mt = 0; mt < 2; mt++)
                #pragma unroll
                for (int nt = 0; nt < 4; nt++)
                    acc[mt][nt] = __builtin_amdgcn_mfma_f32_16x16x32_bf16(bf_[nt][kk], af[mt][kk], acc[mt][nt], 0, 0, 0);
        __builtin_amdgcn_s_barrier();
    }
    #pragma unroll
    for (int mt = 0; mt < 2; mt++) {
        int row = row0 + w * 32 + mt * 16 + col;
        #pragma unroll
        for (int nt = 0; nt < 4; nt++) {
            int cc = col0 + nt * 16 + quad * 4;
            float4 b4 = *(const float4*)&bias[cc];
            float4 h4 = *(const float4*)&hb[(size_t)row * EE + cc];
            bf16x4 o4 = *(const bf16x4*)&ob[(size_t)row * EE + cc];
            float4 out;
            out.x = acc[mt][nt][0] + b4.x + h4.x + (float)o4[0];
            out.y = acc[mt][nt][1] + b4.y + h4.y + (float)o4[1];
            out.z = acc[mt][nt][2] + b4.z + h4.z + (float)o4[2];
            out.w = acc[mt][nt][3] + b4.w + h4.w + (float)o4[3];
            *(float4*)&Cf[(size_t)row * EE + cc] = out;
        }
    }
}

// ---------------------------------------------------------------- launch
extern "C" void kernel_launch(void* const* d_in, const int* in_sizes, int n_in,
                              void* d_out, int out_size, void* d_ws, size_t ws_size,
                              hipStream_t stream) {
    (void)in_sizes; (void)n_in; (void)out_size; (void)ws_size;
    const float* x   = (const float*)d_in[0];
    const float* pos = (const float*)d_in[1];
    const float* Wq  = (const float*)d_in[2];
    const float* Wk  = (const float*)d_in[3];
    const float* Wv  = (const float*)d_in[4];
    const float* W1  = (const float*)d_in[5];
    const float* b1  = (const float*)d_in[6];
    const float* W2  = (const float*)d_in[7];
    const float* b2  = (const float*)d_in[8];

    float* ws = (float*)d_ws;
    size_t N = (size_t)NBSE;
    float* h  = ws;                          // [0 .. 16MB) f32 residual stream
    bf16* ob  = (bf16*)(ws + N);             // [16 .. 24MB) attention out, concat layout
    bf16* qb  = (bf16*)(ws + 2 * N);         // [32 .. 40MB)
    bf16* kb  = qb + N;                      // [40 .. 48MB)
    bf16* vb  = kb + N;                      // [48 .. 56MB) (VT layout [bh][d][s])
    bf16* ffb = (bf16*)(ws + 2 * N);         // [32 .. 64MB) overlays qb,kb,vb (dead by FFN1)
    bf16* W1t = (bf16*)(ws + 4 * N);         // [64MB ..)
    bf16* W2t = W1t + (size_t)LL * EE * FFD;
    bf16* Wqt = W2t + (size_t)LL * EE * FFD;
    bf16* Wkt = Wqt + (size_t)LL * HH * DHD * DHD;
    bf16* Wvt = Wkt + (size_t)LL * HH * DHD * DHD;

    k_prep<<<2144, 256, 0, stream>>>(W1, W2, Wq, Wk, Wv, W1t, W2t, Wqt, Wkt, Wvt);
    for (int l = 0; l < LL; l++) {
        if (l == 0)
            k_lnqkv<true><<<dim3(BB, SS / 64), 256, 0, stream>>>(
                x, pos, h, Wqt, Wkt, Wvt, qb, kb, vb);
        else
            k_lnqkv<false><<<dim3(BB, SS / 64), 256, 0, stream>>>(
                h, nullptr, nullptr,
                Wqt + (size_t)l * HH * DHD * DHD, Wkt + (size_t)l * HH * DHD * DHD,
                Wvt + (size_t)l * HH * DHD * DHD, qb, kb, vb);
        k_attn<<<dim3(BB * HH, SS / 128), 256, 0, stream>>>(qb, kb, vb, ob);
        k_gemm1f<<<dim3(BB * SS / 64, FFD / 256), 256, 0, stream>>>(
            ob, h, W1t + (size_t)l * FFD * EE, b1 + (size_t)l * FFD, ffb);
        float* outp = (l == LL - 1) ? (float*)d_out : h;
        k_gemm2<<<dim3(BB * SS / 128, EE / 64), 256, 0, stream>>>(
            ffb, W2t + (size_t)l * EE * FFD, b2 + (size_t)l * EE, ob, h, outp);
    }
}

// Round 3
// 393.274 us; speedup vs baseline: 1.1670x; 1.1214x over previous
//
#include <hip/hip_runtime.h>
#include <math.h>

// Problem constants
#define BB   32
#define SS   512
#define EE   256
#define HH   8
#define LL   4
#define FFD  1024
#define DHD  32

constexpr float LN_EPS = 1e-5f;
constexpr int   NBSE   = BB * SS * EE;   // 4,194,304

typedef float  f32x4  __attribute__((ext_vector_type(4)));
typedef __bf16 bf16;
typedef __bf16 bf16x4 __attribute__((ext_vector_type(4)));
typedef __bf16 bf16x8 __attribute__((ext_vector_type(8)));

#define WAITV(n) asm volatile("s_waitcnt vmcnt(" #n ")" ::: "memory")

// async global->LDS, 16B per lane; LDS dest is wave-uniform base + lane*16B
__device__ __forceinline__ void glds16(const bf16* g, bf16* l) {
    __builtin_amdgcn_global_load_lds(
        (const __attribute__((address_space(1))) void*)g,
        (__attribute__((address_space(3))) void*)l,
        16, 0, 0);
}

// tanh-form GELU (|err| vs exact erf-GELU ~1e-3, safe within bf16 tolerance)
__device__ __forceinline__ float gelu_f(float x) {
    float u = x * x;
    float t = 1.5957691216057308f * x * (1.0f + 0.044715f * u);
    return x / (1.0f + __expf(-t));
}

// ---------------------------------------------------------------- merged weight prep
__global__ __launch_bounds__(256) void k_prep(const float* __restrict__ W1,
                                              const float* __restrict__ W2,
                                              const float* __restrict__ Wq,
                                              const float* __restrict__ Wk,
                                              const float* __restrict__ Wv,
                                              bf16* __restrict__ W1t,
                                              bf16* __restrict__ W2t,
                                              bf16* __restrict__ Wqt,
                                              bf16* __restrict__ Wkt,
                                              bf16* __restrict__ Wvt) {
    __shared__ float tile[32][33];
    int bid = blockIdx.x;
    int tx = threadIdx.x & 31, ty = threadIdx.x >> 5;   // 32 x 8
    if (bid < 2048) {
        bool isw2 = bid >= 1024;
        int id = isw2 ? bid - 1024 : bid;
        int K = isw2 ? FFD : EE, N = isw2 ? EE : FFD;
        int l = id >> 8, rem = id & 255;
        int n0, k0;
        if (isw2) { n0 = (rem & 7) * 32;  k0 = (rem >> 3) * 32; }
        else      { n0 = (rem & 31) * 32; k0 = (rem >> 5) * 32; }
        const float* in = (isw2 ? W2 : W1) + (size_t)l * K * N;
        bf16* out       = (isw2 ? W2t : W1t) + (size_t)l * K * N;
        #pragma unroll
        for (int i = 0; i < 32; i += 8)
            tile[ty + i][tx] = in[(size_t)(k0 + ty + i) * N + n0 + tx];
        __syncthreads();
        #pragma unroll
        for (int i = 0; i < 32; i += 8)
            out[(size_t)(n0 + ty + i) * K + k0 + tx] = (bf16)tile[tx][ty + i];
    } else {
        int id = bid - 2048;
        int lh = id & 31, z = id >> 5;
        const float* in = (z == 0 ? Wq : z == 1 ? Wk : Wv) + (size_t)lh * 1024;
        bf16* out       = (z == 0 ? Wqt : z == 1 ? Wkt : Wvt) + (size_t)lh * 1024;
        float scale = (z == 0) ? 0.17677669529663687f : 1.0f;
        #pragma unroll
        for (int i = 0; i < 32; i += 8)
            tile[ty + i][tx] = in[(ty + i) * 32 + tx];
        __syncthreads();
        #pragma unroll
        for (int i = 0; i < 32; i += 8)
            out[(ty + i) * 32 + tx] = (bf16)(tile[tx][ty + i] * scale);
    }
}

// ---------------------------------------------------------------- fused (addpos+)LN+QKV (MFMA)
// grid (B, S/32); 4 waves. LN: wave w owns 8 s-rows. MFMA: wave = (rowtile rt=w&1,
// headgroup w>>1 -> 4 heads). 512 blocks -> 2 blocks/CU (was 1).
template <bool ADDPOS>
__global__ __launch_bounds__(256) void k_lnqkv(const float* __restrict__ xin,
                                               const float* __restrict__ pos,
                                               float* __restrict__ hout,
                                               const bf16* __restrict__ Wqt,
                                               const bf16* __restrict__ Wkt,
                                               const bf16* __restrict__ Wvt,
                                               bf16* __restrict__ qb,
                                               bf16* __restrict__ kb,
                                               bf16* __restrict__ vb) {
    __shared__ __attribute__((aligned(16))) bf16 Xs[32 * 264];
    int b = blockIdx.x, s0 = blockIdx.y * 32;
    int tid = threadIdx.x, w = tid >> 6, lane = tid & 63;
    size_t rowoff = ((size_t)(b * SS + s0 + w * 8)) * EE + lane * 4;
    const float* hb = xin + rowoff;
    float4 pv;
    if (ADDPOS) pv = *(const float4*)(pos + lane * 4);
    float4 xr[8];
    #pragma unroll
    for (int i = 0; i < 8; i++)
        xr[i] = *(const float4*)(hb + (size_t)i * EE);
    if (ADDPOS) {
        #pragma unroll
        for (int i = 0; i < 8; i++) {
            xr[i].x += pv.x; xr[i].y += pv.y; xr[i].z += pv.z; xr[i].w += pv.w;
            *(float4*)(hout + rowoff + (size_t)i * EE) = xr[i];
        }
    }
    #pragma unroll
    for (int i = 0; i < 8; i++) {
        float4 v4 = xr[i];
        float sum = v4.x + v4.y + v4.z + v4.w;
        #pragma unroll
        for (int m = 1; m <= 32; m <<= 1) sum += __shfl_xor(sum, m, 64);
        float mean = sum * (1.0f / EE);
        float dx = v4.x - mean, dy = v4.y - mean, dz = v4.z - mean, dw = v4.w - mean;
        float ss = dx * dx + dy * dy + dz * dz + dw * dw;
        #pragma unroll
        for (int m = 1; m <= 32; m <<= 1) ss += __shfl_xor(ss, m, 64);
        float rstd = rsqrtf(ss * (1.0f / EE) + LN_EPS);
        bf16x4 o4 = { (bf16)(dx * rstd), (bf16)(dy * rstd), (bf16)(dz * rstd), (bf16)(dw * rstd) };
        *(bf16x4*)&Xs[(w * 8 + i) * 264 + lane * 4] = o4;
    }
    __syncthreads();
    int col = lane & 15, quad = lane >> 4;
    int rt = w & 1, hgrp = w >> 1;
    #pragma unroll
    for (int hh2 = 0; hh2 < 4; hh2++) {
        int h = hgrp * 4 + hh2;
        bf16x8 a = *(const bf16x8*)&Xs[(rt * 16 + col) * 264 + h * 32 + quad * 8];
        size_t base = ((size_t)((b * HH + h) * SS) + s0 + rt * 16) * DHD;
        #pragma unroll
        for (int nt = 0; nt < 2; nt++) {
            int e = nt * 16 + col;
            bf16x8 bq  = *(const bf16x8*)(Wqt + (h * 32 + e) * 32 + quad * 8);
            bf16x8 bk2 = *(const bf16x8*)(Wkt + (h * 32 + e) * 32 + quad * 8);
            bf16x8 bv2 = *(const bf16x8*)(Wvt + (h * 32 + e) * 32 + quad * 8);
            f32x4 z = {0.f, 0.f, 0.f, 0.f};
            f32x4 cq = __builtin_amdgcn_mfma_f32_16x16x32_bf16(bq, a, z, 0, 0, 0);
            f32x4 ck = __builtin_amdgcn_mfma_f32_16x16x32_bf16(bk2, a, z, 0, 0, 0);
            f32x4 cv = __builtin_amdgcn_mfma_f32_16x16x32_bf16(a, bv2, z, 0, 0, 0);
            bf16x4 q4 = { (bf16)cq[0], (bf16)cq[1], (bf16)cq[2], (bf16)cq[3] };
            bf16x4 k4 = { (bf16)ck[0], (bf16)ck[1], (bf16)ck[2], (bf16)ck[3] };
            size_t tb = base + (size_t)col * DHD + nt * 16 + quad * 4;
            *(bf16x4*)&qb[tb] = q4;
            *(bf16x4*)&kb[tb] = k4;
            bf16x4 vv = { (bf16)cv[0], (bf16)cv[1], (bf16)cv[2], (bf16)cv[3] };
            *(bf16x4*)&vb[(((size_t)(b * HH + h)) * DHD + e) * SS + s0 + rt * 16 + quad * 4] = vv;
        }
    }
}

// ---------------------------------------------------------------- MFMA flash attention v3
#define ATT_LDK 40
#define ATT_LDV 264
#define ATT_LDP 36
__global__ __launch_bounds__(256) void k_attn(const bf16* __restrict__ Q,
                                              const bf16* __restrict__ K,
                                              const bf16* __restrict__ VT,
                                              bf16* __restrict__ O) {
    __shared__ __attribute__((aligned(16))) bf16 Ks[256 * ATT_LDK];
    __shared__ __attribute__((aligned(16))) bf16 Vs[32 * ATT_LDV];
    __shared__ __attribute__((aligned(16))) bf16 Ps[4][16 * ATT_LDP];
    int bh = blockIdx.x;
    int q0 = blockIdx.y * 128;
    int tid = threadIdx.x;
    int w = tid >> 6, lane = tid & 63;
    int col = lane & 15, quad = lane >> 4;
    bf16x8 aq[2];
    #pragma unroll
    for (int sub = 0; sub < 2; sub++)
        aq[sub] = *(const bf16x8*)(Q + ((size_t)(bh * SS + q0 + sub * 64 + w * 16 + col)) * DHD + quad * 8);
    float lr[2] = {0.f, 0.f};
    f32x4 oacc[2][2] = {};
    int ksr = tid >> 2, ksc = (tid & 3) * 8;   // K staging: 64 rows/iter x 32 d
    int vd  = tid >> 5, vso = (tid & 31) * 8;  // VT staging: 8 d-rows/pass x 256 s
    bf16x8 kr[4], vr[4];
    #pragma unroll
    for (int it = 0; it < 4; it++) {
        kr[it] = *(const bf16x8*)(K + ((size_t)(bh * SS + it * 64 + ksr)) * DHD + ksc);
        vr[it] = *(const bf16x8*)(VT + (((size_t)bh * DHD + it * 8 + vd) * SS) + vso);
    }
    for (int ph = 0; ph < 2; ph++) {
        __syncthreads();
        #pragma unroll
        for (int it = 0; it < 4; it++) {
            *(bf16x8*)&Ks[(it * 64 + ksr) * ATT_LDK + ksc] = kr[it];
            *(bf16x8*)&Vs[(it * 8 + vd) * ATT_LDV + vso] = vr[it];
        }
        if (ph == 0) {
            #pragma unroll
            for (int it = 0; it < 4; it++) {
                kr[it] = *(const bf16x8*)(K + ((size_t)(bh * SS + 256 + it * 64 + ksr)) * DHD + ksc);
                vr[it] = *(const bf16x8*)(VT + (((size_t)bh * DHD + it * 8 + vd) * SS) + 256 + vso);
            }
        }
        __syncthreads();
        #pragma unroll
        for (int i = 0; i < 8; i++) {
            bf16x8 bk[2], bv[2];
            #pragma unroll
            for (int nt = 0; nt < 2; nt++) {
                bk[nt] = *(const bf16x8*)&Ks[(i * 32 + nt * 16 + col) * ATT_LDK + quad * 8];
                bv[nt] = *(const bf16x8*)&Vs[(nt * 16 + col) * ATT_LDV + i * 32 + quad * 8];
            }
            __builtin_amdgcn_s_setprio(1);
            #pragma unroll
            for (int sub = 0; sub < 2; sub++) {
                #pragma unroll
                for (int nt = 0; nt < 2; nt++) {
                    f32x4 z = {0.f, 0.f, 0.f, 0.f};
                    f32x4 st = __builtin_amdgcn_mfma_f32_16x16x32_bf16(bk[nt], aq[sub], z, 0, 0, 0);
                    bf16x4 p4;
                    #pragma unroll
                    for (int r = 0; r < 4; r++) {
                        float p = __expf(st[r]);
                        lr[sub] += p;
                        p4[r] = (bf16)p;
                    }
                    *(bf16x4*)&Ps[w][col * ATT_LDP + nt * 16 + quad * 4] = p4;
                }
                bf16x4 apl = *(const bf16x4*)&Ps[w][col * ATT_LDP + quad * 8];
                bf16x4 aph = *(const bf16x4*)&Ps[w][col * ATT_LDP + quad * 8 + 4];
                bf16x8 ap;
                ap[0] = apl[0]; ap[1] = apl[1]; ap[2] = apl[2]; ap[3] = apl[3];
                ap[4] = aph[0]; ap[5] = aph[1]; ap[6] = aph[2]; ap[7] = aph[3];
                #pragma unroll
                for (int nt = 0; nt < 2; nt++)
                    oacc[sub][nt] = __builtin_amdgcn_mfma_f32_16x16x32_bf16(ap, bv[nt], oacc[sub][nt], 0, 0, 0);
            }
            __builtin_amdgcn_s_setprio(0);
        }
    }
    int b = bh >> 3, hh = bh & 7;
    #pragma unroll
    for (int sub = 0; sub < 2; sub++) {
        float ls = lr[sub];
        ls += __shfl_xor(ls, 16, 64);
        ls += __shfl_xor(ls, 32, 64);
        #pragma unroll
        for (int r = 0; r < 4; r++) {
            float lrow = __shfl(ls, quad * 4 + r, 64);
            float inv = 1.0f / lrow;
            int row = q0 + sub * 64 + w * 16 + quad * 4 + r;
            size_t ob = ((size_t)(b * SS + row)) * EE + hh * 32;
            O[ob + col]      = (bf16)(oacc[sub][0][r] * inv);
            O[ob + 16 + col] = (bf16)(oacc[sub][1][r] * inv);
        }
    }
}

// ---------------------------------------------------------------- fully fused FFN
// Per 64-row block: res+LN prologue -> As resident (32KB, XOR-swz). Loop 8 ff-chunks
// of 128: G = gelu(As@W1chunk + b1) -> Gs LDS (16KB, never HBM); out += G@W2chunk
// into persistent acc. Weight staging: 2x32KB ring, counted-vmcnt prefetch
// (B1 unit = 2 glds/thread, B2 unit = 4). 512 thr (8 waves), 112KB LDS, 1 block/CU.
// Saves the 64MB/layer ffb HBM round-trip. Accumulation order bit-identical to the
// previous gemm1f+gemm2 pair.
__global__ __launch_bounds__(512) void k_ffn(const bf16* __restrict__ ob,
                                             const float* __restrict__ hb,
                                             const bf16* __restrict__ W1t_l,
                                             const float* __restrict__ b1_l,
                                             const bf16* __restrict__ W2t_l,
                                             const float* __restrict__ b2_l,
                                             float* __restrict__ Cf) {
    __shared__ __attribute__((aligned(16))) bf16 As[64 * 256];      // 32 KB resident
    __shared__ __attribute__((aligned(16))) bf16 Gs[64 * 128];      // 16 KB
    __shared__ __attribute__((aligned(16))) bf16 Bst[2][16384];     // 2 x 32 KB ring
    __shared__ __attribute__((aligned(16))) float b1s[FFD];         // 4 KB
    int tid = threadIdx.x, w = tid >> 6, lane = tid & 63;
    int col = lane & 15, quad = lane >> 4;
    int rg = w >> 2, cg = w & 3;          // row-group (2x32 rows), col-group
    int row0 = blockIdx.x * 64;

    // b1 -> LDS (broadcast reads later; keeps vmcnt clean in main loop)
    *(float2*)&b1s[tid * 2] = *(const float2*)&b1_l[tid * 2];

    // ---- fused residual + LN prologue: wave w rows w*8 .. w*8+7
    #pragma unroll 2
    for (int rr = 0; rr < 8; rr++) {
        int r = w * 8 + rr;
        size_t g = (size_t)(row0 + r) * EE + lane * 4;
        float4 h4 = *(const float4*)(hb + g);
        bf16x4 o4 = *(const bf16x4*)(ob + g);
        float v0 = h4.x + (float)o4[0], v1 = h4.y + (float)o4[1];
        float v2 = h4.z + (float)o4[2], v3 = h4.w + (float)o4[3];
        float s1 = v0 + v1 + v2 + v3;
        float s2 = v0 * v0 + v1 * v1 + v2 * v2 + v3 * v3;
        #pragma unroll
        for (int m = 1; m <= 32; m <<= 1) {
            s1 += __shfl_xor(s1, m, 64);
            s2 += __shfl_xor(s2, m, 64);
        }
        float mean = s1 * (1.0f / EE);
        float rstd = rsqrtf(s2 * (1.0f / EE) - mean * mean + LN_EPS);
        bf16x4 a4 = { (bf16)((v0 - mean) * rstd), (bf16)((v1 - mean) * rstd),
                      (bf16)((v2 - mean) * rstd), (bf16)((v3 - mean) * rstd) };
        *(bf16x4*)&As[r * 256 + ((lane * 4) ^ ((r & 7) << 3))] = a4;
    }
    asm volatile("s_waitcnt lgkmcnt(0)" ::: "memory");
    __builtin_amdgcn_s_barrier();                       // As, b1s visible
    asm volatile("s_waitcnt vmcnt(0)" ::: "memory");    // drain prologue loads

    int srow = lane >> 3, spos = lane & 7;
    // staging: pre-swizzled source, linear LDS dest (rule #21)
    auto stageB1 = [&](int ch, int p, int slot) {
        #pragma unroll
        for (int i = 0; i < 2; i++) {
            int r = i * 64 + w * 8 + srow;    // ff row within chunk
            glds16(W1t_l + (size_t)(ch * 128 + r) * EE + p * 64 + ((spos ^ (r & 7)) * 8),
                   &Bst[slot][i * 4096 + w * 512]);
        }
    };
    auto stageB2 = [&](int ch, int j, int slot) {
        #pragma unroll
        for (int i = 0; i < 4; i++) {
            int r = i * 64 + w * 8 + srow;    // e row
            glds16(W2t_l + (size_t)r * FFD + ch * 128 + j * 64 + ((spos ^ (r & 7)) * 8),
                   &Bst[slot][i * 4096 + w * 512]);
        }
    };

    f32x4 accO[2][4] = {};
    f32x4 accG[2][2] = {};
    stageB1(0, 0, 0);
    for (int ch = 0; ch < 8; ch++) {
        // ---- W1 phase: 4 units of BK=64 (k = p*64), slot = p&1
        #pragma unroll
        for (int p = 0; p < 4; p++) {
            if (p < 3) { stageB1(ch, p + 1, (p + 1) & 1); WAITV(2); }
            else       { stageB2(ch, 0, 0);               WAITV(4); }
            __builtin_amdgcn_s_barrier();
            bf16x8 af[2][2], bfr[2][2];
            #pragma unroll
            for (int mt = 0; mt < 2; mt++) {
                int r = rg * 32 + mt * 16 + col;
                #pragma unroll
                for (int kk = 0; kk < 2; kk++)
                    af[mt][kk] = *(const bf16x8*)&As[r * 256 + ((p * 64 + kk * 32 + quad * 8) ^ ((r & 7) << 3))];
            }
            #pragma unroll
            for (int nt = 0; nt < 2; nt++) {
                int c = cg * 32 + nt * 16 + col;
                #pragma unroll
                for (int kk = 0; kk < 2; kk++)
                    bfr[nt][kk] = *(const bf16x8*)&Bst[p & 1][c * 64 + ((kk * 32 + quad * 8) ^ ((c & 7) << 3))];
            }
            #pragma unroll
            for (int kk = 0; kk < 2; kk++)
                #pragma unroll
                for (int mt = 0; mt < 2; mt++)
                    #pragma unroll
                    for (int nt = 0; nt < 2; nt++)
                        accG[mt][nt] = __builtin_amdgcn_mfma_f32_16x16x32_bf16(bfr[nt][kk], af[mt][kk], accG[mt][nt], 0, 0, 0);
            if (p == 3) {
                // G = gelu(accG + b1) -> Gs (swizzled); reset accG
                #pragma unroll
                for (int mt = 0; mt < 2; mt++) {
                    int t = rg * 32 + mt * 16 + col;
                    #pragma unroll
                    for (int nt = 0; nt < 2; nt++) {
                        int f = cg * 32 + nt * 16 + quad * 4;
                        float4 b4 = *(const float4*)&b1s[ch * 128 + f];
                        bf16x4 g4;
                        g4[0] = (bf16)gelu_f(accG[mt][nt][0] + b4.x);
                        g4[1] = (bf16)gelu_f(accG[mt][nt][1] + b4.y);
                        g4[2] = (bf16)gelu_f(accG[mt][nt][2] + b4.z);
                        g4[3] = (bf16)gelu_f(accG[mt][nt][3] + b4.w);
                        *(bf16x4*)&Gs[t * 128 + (f ^ ((t & 7) << 3))] = g4;
                        f32x4 z = {0.f, 0.f, 0.f, 0.f};
                        accG[mt][nt] = z;
                    }
                }
                asm volatile("s_waitcnt lgkmcnt(0)" ::: "memory");
            }
            __builtin_amdgcn_s_barrier();
        }
        // ---- W2 phase: 2 units of BK=64 (ffk = j*64), slot = j&1
        #pragma unroll
        for (int j = 0; j < 2; j++) {
            if (j == 0)      { stageB2(ch, 1, 1);     WAITV(4); }
            else if (ch < 7) { stageB1(ch + 1, 0, 0); WAITV(2); }
            else             { WAITV(0); }
            __builtin_amdgcn_s_barrier();
            bf16x8 af2[2][2], bf2[4][2];
            #pragma unroll
            for (int mt = 0; mt < 2; mt++) {
                int r = rg * 32 + mt * 16 + col;
                #pragma unroll
                for (int kk = 0; kk < 2; kk++)
                    af2[mt][kk] = *(const bf16x8*)&Gs[r * 128 + ((j * 64 + kk * 32 + quad * 8) ^ ((r & 7) << 3))];
            }
            #pragma unroll
            for (int nt = 0; nt < 4; nt++) {
                int c = cg * 64 + nt * 16 + col;
                #pragma unroll
                for (int kk = 0; kk < 2; kk++)
                    bf2[nt][kk] = *(const bf16x8*)&Bst[j & 1][c * 64 + ((kk * 32 + quad * 8) ^ ((c & 7) << 3))];
            }
            #pragma unroll
            for (int kk = 0; kk < 2; kk++)
                #pragma unroll
                for (int mt = 0; mt < 2; mt++)
                    #pragma unroll
                    for (int nt = 0; nt < 4; nt++)
                        accO[mt][nt] = __builtin_amdgcn_mfma_f32_16x16x32_bf16(bf2[nt][kk], af2[mt][kk], accO[mt][nt], 0, 0, 0);
            __builtin_amdgcn_s_barrier();
        }
    }
    // ---- epilogue: + b2 + residual (h + ob), f32 out
    #pragma unroll
    for (int mt = 0; mt < 2; mt++) {
        int row = row0 + rg * 32 + mt * 16 + col;
        #pragma unroll
        for (int nt = 0; nt < 4; nt++) {
            int cc = cg * 64 + nt * 16 + quad * 4;
            float4 b4 = *(const float4*)&b2_l[cc];
            float4 h4 = *(const float4*)&hb[(size_t)row * EE + cc];
            bf16x4 o4 = *(const bf16x4*)&ob[(size_t)row * EE + cc];
            float4 out;
            out.x = accO[mt][nt][0] + b4.x + h4.x + (float)o4[0];
            out.y = accO[mt][nt][1] + b4.y + h4.y + (float)o4[1];
            out.z = accO[mt][nt][2] + b4.z + h4.z + (float)o4[2];
            out.w = accO[mt][nt][3] + b4.w + h4.w + (float)o4[3];
            *(float4*)&Cf[(size_t)row * EE + cc] = out;
        }
    }
}

// ---------------------------------------------------------------- launch
extern "C" void kernel_launch(void* const* d_in, const int* in_sizes, int n_in,
                              void* d_out, int out_size, void* d_ws, size_t ws_size,
                              hipStream_t stream) {
    (void)in_sizes; (void)n_in; (void)out_size; (void)ws_size;
    const float* x   = (const float*)d_in[0];
    const float* pos = (const float*)d_in[1];
    const float* Wq  = (const float*)d_in[2];
    const float* Wk  = (const float*)d_in[3];
    const float* Wv  = (const float*)d_in[4];
    const float* W1  = (const float*)d_in[5];
    const float* b1  = (const float*)d_in[6];
    const float* W2  = (const float*)d_in[7];
    const float* b2  = (const float*)d_in[8];

    float* ws = (float*)d_ws;
    size_t N = (size_t)NBSE;
    float* h  = ws;                          // [0 .. 16MB) f32 residual stream
    bf16* ob  = (bf16*)(ws + N);             // [16 .. 24MB) attention out, concat layout
    bf16* qb  = (bf16*)(ws + 2 * N);         // [32 .. 40MB)
    bf16* kb  = qb + N;                      // [40 .. 48MB)
    bf16* vb  = kb + N;                      // [48 .. 56MB) (VT layout [bh][d][s])
    bf16* W1t = (bf16*)(ws + 4 * N);         // [64MB ..)
    bf16* W2t = W1t + (size_t)LL * EE * FFD;
    bf16* Wqt = W2t + (size_t)LL * EE * FFD;
    bf16* Wkt = Wqt + (size_t)LL * HH * DHD * DHD;
    bf16* Wvt = Wkt + (size_t)LL * HH * DHD * DHD;

    k_prep<<<2144, 256, 0, stream>>>(W1, W2, Wq, Wk, Wv, W1t, W2t, Wqt, Wkt, Wvt);
    for (int l = 0; l < LL; l++) {
        if (l == 0)
            k_lnqkv<true><<<dim3(BB, SS / 32), 256, 0, stream>>>(
                x, pos, h, Wqt, Wkt, Wvt, qb, kb, vb);
        else
            k_lnqkv<false><<<dim3(BB, SS / 32), 256, 0, stream>>>(
                h, nullptr, nullptr,
                Wqt + (size_t)l * HH * DHD * DHD, Wkt + (size_t)l * HH * DHD * DHD,
                Wvt + (size_t)l * HH * DHD * DHD, qb, kb, vb);
        k_attn<<<dim3(BB * HH, SS / 128), 256, 0, stream>>>(qb, kb, vb, ob);
        float* outp = (l == LL - 1) ? (float*)d_out : h;
        k_ffn<<<BB * SS / 64, 512, 0, stream>>>(
            ob, h, W1t + (size_t)l * FFD * EE, b1 + (size_t)l * FFD,
            W2t + (size_t)l * EE * FFD, b2 + (size_t)l * EE, outp);
    }
}